// Round 11
// baseline (195.349 us; speedup 1.0000x reference)
//
#include <hip/hip_runtime.h>
#include <math.h>

// ---------------------------------------------------------------------------
// 2-layer GCN:  out = gcn(relu(gcn(x, W1, b1)), W2, b2)
// gcn(x,W,b)[c] = dinv[c] * ( dinv[c]*xw[c] + sum_{edges r->c} dinv[r]*xw[r] ) + b
//   where xw = x @ W (UNSCALED in y buffers), dinv = rsqrt(1 + indeg)
// No scan: fixed-capacity CSR slots (srcidx[c*CAP + rank[e]]), rank = return
// of the degree-count atomicAdd. GEMM1's two column panels are fused under
// the two CSR-build phases (count, fill) so neither latency phase is exposed.
// ---------------------------------------------------------------------------

typedef _Float16 h8 __attribute__((ext_vector_type(8)));
typedef float    f32x4 __attribute__((ext_vector_type(4)));

#define CAP 64   // slots per node; overflow list handles adversarial degrees

// init: zero deg/govf (blocks [0,zb)) + both weight transposes (rest)
__global__ void k_init(int* __restrict__ deg, int* __restrict__ govf, int N,
                       const float* __restrict__ W1, const float* __restrict__ W2,
                       _Float16* __restrict__ wt1, _Float16* __restrict__ wt2,
                       int K, int n1, int n2, int zb)
{
    if ((int)blockIdx.x < zb) {
        int i = blockIdx.x * blockDim.x + threadIdx.x;
        if (i < N) deg[i] = 0;
        if (blockIdx.x == 0 && threadIdx.x == 0) *govf = 0;
    } else {
        int i = (blockIdx.x - zb) * blockDim.x + threadIdx.x;
        int c1 = K * n1;
        if (i < c1) {
            int k = i / n1, n = i % n1;
            wt1[(long)n * K + k] = (_Float16)W1[i];
        } else if (i < c1 + K * n2) {
            int j = i - c1;
            int k = j / n2, n = j % n2;
            wt2[(long)n * K + k] = (_Float16)W2[j];
        }
    }
}

// ---- shared GEMM body (register-prefetch pipelined, UNSCALED output) ----
// Y[m][n] = fp16( sum_k X[m][k] * Wt[n][k] )
// 128x128 block tile, BK=32, 4 waves (2x2), each wave 64x64 via 4x4
// mfma_f32_16x16x32_f16 fragments. A32: read X as fp32, convert at commit.
template<bool A32>
__device__ __forceinline__ void gemm_body(
    const float* __restrict__ X32, const _Float16* __restrict__ X16,
    const _Float16* __restrict__ Wt, _Float16* __restrict__ Y,
    int M, int K, int NC, int bx, int by)
{
    __shared__ _Float16 As[128][40];  // row stride 80B (16B-aligned)
    __shared__ _Float16 Bs[128][40];

    const int bn = bx * 128;
    const int bm = by * 128;
    const int tid = threadIdx.x;
    const int w = tid >> 6, l = tid & 63;
    const int wm = (w >> 1) * 64, wn = (w & 1) * 64;
    const int lr = l & 15, lg = l >> 4;

    const int arow = tid >> 2, acol = (tid & 3) * 8;   // A32 loader
    const int xrow = tid >> 1, xcol = (tid & 1) * 16;  // fp16 A / B loader

    f32x4 acc[4][4];
    #pragma unroll
    for (int i = 0; i < 4; i++)
        #pragma unroll
        for (int j = 0; j < 4; j++)
            acc[i][j] = (f32x4){0.f, 0.f, 0.f, 0.f};

    float4 pf0, pf1, pf2, pf3;   // A32 prefetch regs
    h8 pa0, pa1;                 // fp16-A prefetch regs
    h8 pb0, pb1;                 // B prefetch regs

    auto loadA = [&](int k0) {
        if (A32) {
            int gm0 = bm + arow;      if (gm0 >= M) gm0 = M - 1;
            int gm1 = bm + 64 + arow; if (gm1 >= M) gm1 = M - 1;
            pf0 = *reinterpret_cast<const float4*>(&X32[(long)gm0 * K + k0 + acol]);
            pf1 = *reinterpret_cast<const float4*>(&X32[(long)gm0 * K + k0 + acol + 4]);
            pf2 = *reinterpret_cast<const float4*>(&X32[(long)gm1 * K + k0 + acol]);
            pf3 = *reinterpret_cast<const float4*>(&X32[(long)gm1 * K + k0 + acol + 4]);
        } else {
            int gm = bm + xrow; if (gm >= M) gm = M - 1;
            pa0 = *reinterpret_cast<const h8*>(&X16[(long)gm * K + k0 + xcol]);
            pa1 = *reinterpret_cast<const h8*>(&X16[(long)gm * K + k0 + xcol + 8]);
        }
    };
    auto loadB = [&](int k0) {
        pb0 = *reinterpret_cast<const h8*>(&Wt[(long)(bn + xrow) * K + k0 + xcol]);
        pb1 = *reinterpret_cast<const h8*>(&Wt[(long)(bn + xrow) * K + k0 + xcol + 8]);
    };

    loadA(0); loadB(0);
    for (int k0 = 0; k0 < K; k0 += 32) {
        // commit staged regs to LDS
        if (A32) {
            h8 h0, h1;
            h0[0] = (_Float16)pf0.x; h0[1] = (_Float16)pf0.y;
            h0[2] = (_Float16)pf0.z; h0[3] = (_Float16)pf0.w;
            h0[4] = (_Float16)pf1.x; h0[5] = (_Float16)pf1.y;
            h0[6] = (_Float16)pf1.z; h0[7] = (_Float16)pf1.w;
            h1[0] = (_Float16)pf2.x; h1[1] = (_Float16)pf2.y;
            h1[2] = (_Float16)pf2.z; h1[3] = (_Float16)pf2.w;
            h1[4] = (_Float16)pf3.x; h1[5] = (_Float16)pf3.y;
            h1[6] = (_Float16)pf3.z; h1[7] = (_Float16)pf3.w;
            *reinterpret_cast<h8*>(&As[arow][acol]) = h0;
            *reinterpret_cast<h8*>(&As[64 + arow][acol]) = h1;
        } else {
            *reinterpret_cast<h8*>(&As[xrow][xcol]) = pa0;
            *reinterpret_cast<h8*>(&As[xrow][xcol + 8]) = pa1;
        }
        *reinterpret_cast<h8*>(&Bs[xrow][xcol]) = pb0;
        *reinterpret_cast<h8*>(&Bs[xrow][xcol + 8]) = pb1;
        __syncthreads();

        // prefetch next K-tile while computing this one
        if (k0 + 32 < K) { loadA(k0 + 32); loadB(k0 + 32); }

        h8 a[4], b[4];
        #pragma unroll
        for (int i = 0; i < 4; i++)
            a[i] = *reinterpret_cast<const h8*>(&As[wm + i * 16 + lr][lg * 8]);
        #pragma unroll
        for (int j = 0; j < 4; j++)
            b[j] = *reinterpret_cast<const h8*>(&Bs[wn + j * 16 + lr][lg * 8]);
        #pragma unroll
        for (int i = 0; i < 4; i++)
            #pragma unroll
            for (int j = 0; j < 4; j++)
                acc[i][j] = __builtin_amdgcn_mfma_f32_16x16x32_f16(
                    a[i], b[j], acc[i][j], 0, 0, 0);
        __syncthreads();
    }

    // C layout: row = (l>>4)*4 + reg, col = l&15 ; unscaled store
    #pragma unroll
    for (int i = 0; i < 4; i++) {
        #pragma unroll
        for (int r = 0; r < 4; r++) {
            int gm = bm + wm + i * 16 + lg * 4 + r;
            if (gm < M) {
                #pragma unroll
                for (int j = 0; j < 4; j++)
                    Y[(long)gm * NC + bn + wn + j * 16 + lr] =
                        (_Float16)acc[i][j][r];
            }
        }
    }
}

// Launch A: blocks [0,ncb) = degree count (record ranks); rest = GEMM1 panel
// columns [bx0*128, (bx0+gxA)*128).
__global__ __launch_bounds__(256) void k_count_gemm(
    const int* __restrict__ col, int E, int* __restrict__ deg, int* __restrict__ rank,
    int ncb,
    const float* __restrict__ X32, const _Float16* __restrict__ Wt,
    _Float16* __restrict__ Y, int M, int K, int NC, int gxA, int bx0)
{
    if ((int)blockIdx.x < ncb) {
        int i = blockIdx.x * blockDim.x + threadIdx.x;
        int s = ncb * blockDim.x;
        for (int e = i; e < E; e += s) rank[e] = atomicAdd(&deg[col[e]], 1);
        return;
    }
    int gb = blockIdx.x - ncb;
    gemm_body<true>(X32, nullptr, Wt, Y, M, K, NC, bx0 + gb % gxA, gb / gxA);
}

// Launch B: blocks [0,zb) = dinv; [zb, zb+nfb) = atomic-free slot fill;
// rest = GEMM1 panel columns [bx0*128, ...).
__global__ __launch_bounds__(256) void k_fill_gemm(
    const int* __restrict__ row, const int* __restrict__ col,
    const int* __restrict__ rank, int E,
    const int* __restrict__ deg, float* __restrict__ dinv, int N,
    int* __restrict__ srcidx, int2* __restrict__ ovf, int* __restrict__ govf,
    int zb, int nfb,
    const float* __restrict__ X32, const _Float16* __restrict__ Wt,
    _Float16* __restrict__ Y, int M, int K, int NC, int gxB, int bx0)
{
    if ((int)blockIdx.x < zb) {
        int i = blockIdx.x * blockDim.x + threadIdx.x;
        if (i < N) dinv[i] = rsqrtf(1.f + (float)deg[i]);
        return;
    }
    if ((int)blockIdx.x < zb + nfb) {
        int g = (blockIdx.x - zb) * blockDim.x + threadIdx.x;
        int nthreads = nfb * blockDim.x;
        if ((E & 3) == 0) {
            int G4 = E >> 2;
            for (int q = g; q < G4; q += nthreads) {
                int e = q << 2;
                int4 c4 = *reinterpret_cast<const int4*>(&col[e]);
                int4 r4 = *reinterpret_cast<const int4*>(&row[e]);
                int4 k4 = *reinterpret_cast<const int4*>(&rank[e]);
                if (k4.x < CAP) srcidx[c4.x * CAP + k4.x] = r4.x;
                else { int o = atomicAdd(govf, 1); ovf[o] = make_int2(r4.x, c4.x); }
                if (k4.y < CAP) srcidx[c4.y * CAP + k4.y] = r4.y;
                else { int o = atomicAdd(govf, 1); ovf[o] = make_int2(r4.y, c4.y); }
                if (k4.z < CAP) srcidx[c4.z * CAP + k4.z] = r4.z;
                else { int o = atomicAdd(govf, 1); ovf[o] = make_int2(r4.z, c4.z); }
                if (k4.w < CAP) srcidx[c4.w * CAP + k4.w] = r4.w;
                else { int o = atomicAdd(govf, 1); ovf[o] = make_int2(r4.w, c4.w); }
            }
        } else {
            for (int e = g; e < E; e += nthreads) {
                int c = col[e], r = row[e], k = rank[e];
                if (k < CAP) srcidx[c * CAP + k] = r;
                else { int o = atomicAdd(govf, 1); ovf[o] = make_int2(r, c); }
            }
        }
        return;
    }
    int gb = blockIdx.x - zb - nfb;
    gemm_body<true>(X32, nullptr, Wt, Y, M, K, NC, bx0 + gb % gxB, gb / gxB);
}

__global__ __launch_bounds__(256) void k_gemm16(
    const _Float16* __restrict__ X16, const _Float16* __restrict__ Wt,
    _Float16* __restrict__ Y, int M, int K, int NC)
{
    gemm_body<false>(nullptr, X16, Wt, Y, M, K, NC, blockIdx.x, blockIdx.y);
}

// out[node][fo:fo+128] = act( dc*( dc*Y[node] + sum_e dinv[r]*Y[r] ) + bias )
// One wave per node, slot-CSR. LPR lanes per row slice (16B/lane);
// G = 64/LPR edges per batch, 4-batch unroll.
template<int LPR, bool F16OUT, bool RELU>
__global__ __launch_bounds__(256) void k_agg(
    const int* __restrict__ deg, const float* __restrict__ dinv,
    const int* __restrict__ srcidx,
    const int2* __restrict__ ovf, const int* __restrict__ govf,
    const _Float16* __restrict__ Y, const float* __restrict__ bias,
    int N, int FT, int fo,
    float* __restrict__ out32, _Float16* __restrict__ out16)
{
    const int G = 64 / LPR;   // edges per batch
    int node = blockIdx.x * 4 + (threadIdx.x >> 6);
    if (node >= N) return;
    int lane = threadIdx.x & 63;
    int sub = lane / LPR;
    int fl  = lane % LPR;
    const int fcol = fo + fl * 8;

    float dc = dinv[node];
    int cnt = min(deg[node], CAP);
    const int beg = node * CAP;

    float acc[8];
    if (sub == 0) {  // self loop (scaled by dc; outer dc applied at the end)
        h8 v = *reinterpret_cast<const h8*>(&Y[(long)node * FT + fcol]);
        #pragma unroll
        for (int j = 0; j < 8; j++) acc[j] = dc * (float)v[j];
    } else {
        #pragma unroll
        for (int j = 0; j < 8; j++) acc[j] = 0.f;
    }

    int i = sub;
    int full = cnt / (4 * G);
    for (int t = 0; t < full; t++) {
        int r0 = srcidx[beg + i];
        int r1 = srcidx[beg + i + G];
        int r2 = srcidx[beg + i + 2 * G];
        int r3 = srcidx[beg + i + 3 * G];
        float d0 = dinv[r0], d1 = dinv[r1], d2 = dinv[r2], d3 = dinv[r3];
        h8 v0 = *reinterpret_cast<const h8*>(&Y[(long)r0 * FT + fcol]);
        h8 v1 = *reinterpret_cast<const h8*>(&Y[(long)r1 * FT + fcol]);
        h8 v2 = *reinterpret_cast<const h8*>(&Y[(long)r2 * FT + fcol]);
        h8 v3 = *reinterpret_cast<const h8*>(&Y[(long)r3 * FT + fcol]);
        #pragma unroll
        for (int j = 0; j < 8; j++)
            acc[j] += (d0 * (float)v0[j] + d1 * (float)v1[j]) +
                      (d2 * (float)v2[j] + d3 * (float)v3[j]);
        i += 4 * G;
    }
    for (; i < cnt; i += G) {
        int r = srcidx[beg + i];
        float d = dinv[r];
        h8 v = *reinterpret_cast<const h8*>(&Y[(long)r * FT + fcol]);
        #pragma unroll
        for (int j = 0; j < 8; j++) acc[j] += d * (float)v[j];
    }
    {   // capacity-overflow edges (normally zero)
        int no = *govf;
        for (int t = sub; t < no; t += G) {
            int2 pr = ovf[t];
            if (pr.y == node) {
                float d = dinv[pr.x];
                h8 v = *reinterpret_cast<const h8*>(&Y[(long)pr.x * FT + fcol]);
                #pragma unroll
                for (int j = 0; j < 8; j++) acc[j] += d * (float)v[j];
            }
        }
    }

    // merge sub-groups
    #pragma unroll
    for (int m = LPR; m < 64; m <<= 1)
        #pragma unroll
        for (int j = 0; j < 8; j++)
            acc[j] += __shfl_xor(acc[j], m, 64);

    const float4* b4 = reinterpret_cast<const float4*>(&bias[fcol]);
    float4 blo = b4[0], bhi = b4[1];
    float r8[8];
    r8[0] = fmaf(dc, acc[0], blo.x); r8[1] = fmaf(dc, acc[1], blo.y);
    r8[2] = fmaf(dc, acc[2], blo.z); r8[3] = fmaf(dc, acc[3], blo.w);
    r8[4] = fmaf(dc, acc[4], bhi.x); r8[5] = fmaf(dc, acc[5], bhi.y);
    r8[6] = fmaf(dc, acc[6], bhi.z); r8[7] = fmaf(dc, acc[7], bhi.w);
    if (RELU) {
        #pragma unroll
        for (int j = 0; j < 8; j++) r8[j] = fmaxf(r8[j], 0.f);
    }

    long base = (long)node * FT + fcol;
    if (F16OUT) {
        if (sub == 0) {
            h8 o;
            #pragma unroll
            for (int j = 0; j < 8; j++) o[j] = (_Float16)r8[j];
            *reinterpret_cast<h8*>(&out16[base]) = o;
        }
    } else {
        if (sub == 0) {
            *reinterpret_cast<float4*>(&out32[base]) =
                make_float4(r8[0], r8[1], r8[2], r8[3]);
        } else if (sub == 1) {
            *reinterpret_cast<float4*>(&out32[base + 4]) =
                make_float4(r8[4], r8[5], r8[6], r8[7]);
        }
    }
}

extern "C" void kernel_launch(void* const* d_in, const int* in_sizes, int n_in,
                              void* d_out, int out_size, void* d_ws, size_t ws_size,
                              hipStream_t stream)
{
    const float* x   = (const float*)d_in[0];
    const int*   ei  = (const int*)d_in[1];
    const float* W1  = (const float*)d_in[2];
    const float* b1  = (const float*)d_in[3];
    const float* W2  = (const float*)d_in[4];
    const float* b2  = (const float*)d_in[5];

    const int nhid  = in_sizes[3];            // 256
    const int nfeat = in_sizes[5];            // 128
    const int N     = in_sizes[0] / nhid;     // 50000
    const int E     = in_sizes[1] / 2;        // 800000

    const int* row = ei;        // source
    const int* col = ei + E;    // target

    size_t cur = 0;
    auto alloc = [&](size_t bytes) {
        void* p = (char*)d_ws + cur;
        cur += (bytes + 255) & ~(size_t)255;
        return p;
    };
    float*     dinv   = (float*)alloc((size_t)N * 4);
    int*       deg_i  = (int*)alloc((size_t)N * 4);
    int*       rank   = (int*)alloc((size_t)E * 4);
    int*       srcidx = (int*)alloc((size_t)N * CAP * 4);
    int2*      ovf    = (int2*)alloc((size_t)E * 8);
    int*       govf   = (int*)alloc(256);
    _Float16*  wt1    = (_Float16*)alloc((size_t)nhid * nhid * 2);
    _Float16*  wt2    = (_Float16*)alloc((size_t)nhid * nfeat * 2);
    _Float16*  y16    = (_Float16*)alloc((size_t)N * nhid * 2);   // xw (unscaled)
    _Float16*  h16    = (_Float16*)alloc((size_t)N * nhid * 2);   // relu output
    _Float16*  y2     = (_Float16*)alloc((size_t)N * nfeat * 2);  // hw (unscaled)
    float*     out    = (float*)d_out;
    (void)ws_size; (void)n_in; (void)out_size;

    const int T = 256;
    const int zb = (N + T - 1) / T;
    const int gx = nhid / 128;                // GEMM1 column panels (2)
    const int gy = (N + 127) / 128;
    const int gxA = (gx + 1) / 2;             // panels under launch A
    const int gxB = gx - gxA;                 // panels under launch B

    // ---- init (zero deg + weight transposes, one launch) ----
    {
        int pb = (nhid * (nhid + nfeat) + T - 1) / T;
        k_init<<<zb + pb, T, 0, stream>>>(deg_i, govf, N, W1, W2, wt1, wt2,
                                          nhid, nhid, nfeat, zb);
    }

    // ---- launch A: degree count + rank (512 blocks) || GEMM1 panel 0 ----
    {
        const int ncb = 512;
        k_count_gemm<<<ncb + gxA * gy, T, 0, stream>>>(
            col, E, deg_i, rank, ncb, x, wt1, y16, N, nhid, nhid, gxA, 0);
    }

    // ---- launch B: dinv || slot fill (1024 blocks) || GEMM1 panel 1 ----
    {
        const int nfb = 1024;
        k_fill_gemm<<<zb + nfb + gxB * gy, T, 0, stream>>>(
            row, col, rank, E, deg_i, dinv, N, srcidx, ovf, govf, zb, nfb,
            x, wt1, y16, N, nhid, nhid, gxB, gxA);
    }

    // ---- layer 1 aggregation: two feature-half passes ----
    k_agg<16, true, true><<<(N + 3) / 4, T, 0, stream>>>(
        deg_i, dinv, srcidx, ovf, govf, y16, b1, N, nhid, 0, nullptr, h16);
    k_agg<16, true, true><<<(N + 3) / 4, T, 0, stream>>>(
        deg_i, dinv, srcidx, ovf, govf, y16, b1, N, nhid, 128, nullptr, h16);

    // ---- layer 2 ----
    {
        dim3 grid(nfeat / 128, (N + 127) / 128);
        k_gemm16<<<grid, T, 0, stream>>>(h16, wt2, y2, N, nhid, nfeat);
    }
    k_agg<16, false, false><<<(N + 3) / 4, T, 0, stream>>>(
        deg_i, dinv, srcidx, ovf, govf, y2, b2, N, nfeat, 0, out, nullptr);
}

// Round 12
// 187.013 us; speedup vs baseline: 1.0446x; 1.0446x over previous
//
#include <hip/hip_runtime.h>
#include <math.h>

// ---------------------------------------------------------------------------
// 2-layer GCN:  out = gcn(relu(gcn(x, W1, b1)), W2, b2)
// gcn(x,W,b)[c] = dinv[c] * ( dinv[c]*xw[c] + sum_{edges r->c} dinv[r]*xw[r] ) + b
//   where xw = x @ W (UNSCALED in y buffers), dinv = rsqrt(1 + indeg)
// Slot-CSR (no scan): srcidx[c*CAP + rank[e]], rank = degree-count atomicAdd
// return. Structure: memset(deg) -> count(1024 blk)+W-prep -> GEMM1||fill ->
// agg1 (both halves, 1 launch) -> GEMM2 -> agg2.
// ---------------------------------------------------------------------------

typedef _Float16 h8 __attribute__((ext_vector_type(8)));
typedef float    f32x4 __attribute__((ext_vector_type(4)));

#define CAP 64   // slots per node; overflow list handles adversarial degrees

// ---- shared GEMM body (register-prefetch pipelined, UNSCALED output) ----
// Y[m][n] = fp16( sum_k X[m][k] * Wt[n][k] )
// 128x128 block tile, BK=32, 4 waves (2x2), each wave 64x64 via 4x4
// mfma_f32_16x16x32_f16 fragments. A32: read X as fp32, convert at commit.
template<bool A32>
__device__ __forceinline__ void gemm_body(
    const float* __restrict__ X32, const _Float16* __restrict__ X16,
    const _Float16* __restrict__ Wt, _Float16* __restrict__ Y,
    int M, int K, int NC, int bx, int by)
{
    __shared__ _Float16 As[128][40];  // row stride 80B (16B-aligned)
    __shared__ _Float16 Bs[128][40];

    const int bn = bx * 128;
    const int bm = by * 128;
    const int tid = threadIdx.x;
    const int w = tid >> 6, l = tid & 63;
    const int wm = (w >> 1) * 64, wn = (w & 1) * 64;
    const int lr = l & 15, lg = l >> 4;

    const int arow = tid >> 2, acol = (tid & 3) * 8;   // A32 loader
    const int xrow = tid >> 1, xcol = (tid & 1) * 16;  // fp16 A / B loader

    f32x4 acc[4][4];
    #pragma unroll
    for (int i = 0; i < 4; i++)
        #pragma unroll
        for (int j = 0; j < 4; j++)
            acc[i][j] = (f32x4){0.f, 0.f, 0.f, 0.f};

    float4 pf0, pf1, pf2, pf3;   // A32 prefetch regs
    h8 pa0, pa1;                 // fp16-A prefetch regs
    h8 pb0, pb1;                 // B prefetch regs

    auto loadA = [&](int k0) {
        if (A32) {
            int gm0 = bm + arow;      if (gm0 >= M) gm0 = M - 1;
            int gm1 = bm + 64 + arow; if (gm1 >= M) gm1 = M - 1;
            pf0 = *reinterpret_cast<const float4*>(&X32[(long)gm0 * K + k0 + acol]);
            pf1 = *reinterpret_cast<const float4*>(&X32[(long)gm0 * K + k0 + acol + 4]);
            pf2 = *reinterpret_cast<const float4*>(&X32[(long)gm1 * K + k0 + acol]);
            pf3 = *reinterpret_cast<const float4*>(&X32[(long)gm1 * K + k0 + acol + 4]);
        } else {
            int gm = bm + xrow; if (gm >= M) gm = M - 1;
            pa0 = *reinterpret_cast<const h8*>(&X16[(long)gm * K + k0 + xcol]);
            pa1 = *reinterpret_cast<const h8*>(&X16[(long)gm * K + k0 + xcol + 8]);
        }
    };
    auto loadB = [&](int k0) {
        pb0 = *reinterpret_cast<const h8*>(&Wt[(long)(bn + xrow) * K + k0 + xcol]);
        pb1 = *reinterpret_cast<const h8*>(&Wt[(long)(bn + xrow) * K + k0 + xcol + 8]);
    };

    loadA(0); loadB(0);
    for (int k0 = 0; k0 < K; k0 += 32) {
        // commit staged regs to LDS
        if (A32) {
            h8 h0, h1;
            h0[0] = (_Float16)pf0.x; h0[1] = (_Float16)pf0.y;
            h0[2] = (_Float16)pf0.z; h0[3] = (_Float16)pf0.w;
            h0[4] = (_Float16)pf1.x; h0[5] = (_Float16)pf1.y;
            h0[6] = (_Float16)pf1.z; h0[7] = (_Float16)pf1.w;
            h1[0] = (_Float16)pf2.x; h1[1] = (_Float16)pf2.y;
            h1[2] = (_Float16)pf2.z; h1[3] = (_Float16)pf2.w;
            h1[4] = (_Float16)pf3.x; h1[5] = (_Float16)pf3.y;
            h1[6] = (_Float16)pf3.z; h1[7] = (_Float16)pf3.w;
            *reinterpret_cast<h8*>(&As[arow][acol]) = h0;
            *reinterpret_cast<h8*>(&As[64 + arow][acol]) = h1;
        } else {
            *reinterpret_cast<h8*>(&As[xrow][xcol]) = pa0;
            *reinterpret_cast<h8*>(&As[xrow][xcol + 8]) = pa1;
        }
        *reinterpret_cast<h8*>(&Bs[xrow][xcol]) = pb0;
        *reinterpret_cast<h8*>(&Bs[xrow][xcol + 8]) = pb1;
        __syncthreads();

        // prefetch next K-tile while computing this one
        if (k0 + 32 < K) { loadA(k0 + 32); loadB(k0 + 32); }

        h8 a[4], b[4];
        #pragma unroll
        for (int i = 0; i < 4; i++)
            a[i] = *reinterpret_cast<const h8*>(&As[wm + i * 16 + lr][lg * 8]);
        #pragma unroll
        for (int j = 0; j < 4; j++)
            b[j] = *reinterpret_cast<const h8*>(&Bs[wn + j * 16 + lr][lg * 8]);
        #pragma unroll
        for (int i = 0; i < 4; i++)
            #pragma unroll
            for (int j = 0; j < 4; j++)
                acc[i][j] = __builtin_amdgcn_mfma_f32_16x16x32_f16(
                    a[i], b[j], acc[i][j], 0, 0, 0);
        __syncthreads();
    }

    // C layout: row = (l>>4)*4 + reg, col = l&15 ; unscaled store
    #pragma unroll
    for (int i = 0; i < 4; i++) {
        #pragma unroll
        for (int r = 0; r < 4; r++) {
            int gm = bm + wm + i * 16 + lg * 4 + r;
            if (gm < M) {
                #pragma unroll
                for (int j = 0; j < 4; j++)
                    Y[(long)gm * NC + bn + wn + j * 16 + lr] =
                        (_Float16)acc[i][j][r];
            }
        }
    }
}

// count (1024 blocks, the empirically-fast standalone shape) + weight prep
__global__ __launch_bounds__(256) void k_count_prep(
    const int* __restrict__ col, int E, int* __restrict__ deg, int* __restrict__ rank,
    int ncb,
    const float* __restrict__ W1, const float* __restrict__ W2,
    _Float16* __restrict__ wt1, _Float16* __restrict__ wt2,
    int K, int n1, int n2)
{
    if ((int)blockIdx.x < ncb) {
        int i = blockIdx.x * blockDim.x + threadIdx.x;
        int s = ncb * blockDim.x;
        for (int e = i; e < E; e += s) rank[e] = atomicAdd(&deg[col[e]], 1);
        return;
    }
    int i = (blockIdx.x - ncb) * blockDim.x + threadIdx.x;
    int c1 = K * n1;
    if (i < c1) {
        int k = i / n1, n = i % n1;
        wt1[(long)n * K + k] = (_Float16)W1[i];
    } else if (i < c1 + K * n2) {
        int j = i - c1;
        int k = j / n2, n = j % n2;
        wt2[(long)n * K + k] = (_Float16)W2[j];
    }
}

// Fused: blocks [0,ngb) = GEMM1 tiles (scheduled first, the long pole);
// [ngb, ngb+zb) = dinv; rest = atomic-free slot fill.
__global__ __launch_bounds__(256) void k_gemm_fill(
    const float* __restrict__ X32, const _Float16* __restrict__ Wt,
    _Float16* __restrict__ Y, int M, int K, int NC, int ngb, int gx,
    const int* __restrict__ row, const int* __restrict__ col,
    const int* __restrict__ rank, int E,
    const int* __restrict__ deg, float* __restrict__ dinv, int N,
    int* __restrict__ srcidx, int2* __restrict__ ovf, int* __restrict__ govf,
    int zb)
{
    if ((int)blockIdx.x < ngb) {
        int gb = blockIdx.x;
        gemm_body<true>(X32, nullptr, Wt, Y, M, K, NC, gb % gx, gb / gx);
        return;
    }
    if ((int)blockIdx.x < ngb + zb) {
        int i = (blockIdx.x - ngb) * blockDim.x + threadIdx.x;
        if (i < N) dinv[i] = rsqrtf(1.f + (float)deg[i]);
        return;
    }
    int g = (blockIdx.x - ngb - zb) * blockDim.x + threadIdx.x;
    int nthreads = (gridDim.x - ngb - zb) * blockDim.x;
    if ((E & 3) == 0) {
        int G4 = E >> 2;
        for (int q = g; q < G4; q += nthreads) {
            int e = q << 2;
            int4 c4 = *reinterpret_cast<const int4*>(&col[e]);
            int4 r4 = *reinterpret_cast<const int4*>(&row[e]);
            int4 k4 = *reinterpret_cast<const int4*>(&rank[e]);
            if (k4.x < CAP) srcidx[c4.x * CAP + k4.x] = r4.x;
            else { int o = atomicAdd(govf, 1); ovf[o] = make_int2(r4.x, c4.x); }
            if (k4.y < CAP) srcidx[c4.y * CAP + k4.y] = r4.y;
            else { int o = atomicAdd(govf, 1); ovf[o] = make_int2(r4.y, c4.y); }
            if (k4.z < CAP) srcidx[c4.z * CAP + k4.z] = r4.z;
            else { int o = atomicAdd(govf, 1); ovf[o] = make_int2(r4.z, c4.z); }
            if (k4.w < CAP) srcidx[c4.w * CAP + k4.w] = r4.w;
            else { int o = atomicAdd(govf, 1); ovf[o] = make_int2(r4.w, c4.w); }
        }
    } else {
        for (int e = g; e < E; e += nthreads) {
            int c = col[e], r = row[e], k = rank[e];
            if (k < CAP) srcidx[c * CAP + k] = r;
            else { int o = atomicAdd(govf, 1); ovf[o] = make_int2(r, c); }
        }
    }
}

__global__ __launch_bounds__(256) void k_gemm16(
    const _Float16* __restrict__ X16, const _Float16* __restrict__ Wt,
    _Float16* __restrict__ Y, int M, int K, int NC)
{
    gemm_body<false>(nullptr, X16, Wt, Y, M, K, NC, blockIdx.x, blockIdx.y);
}

// out[node][fo:fo+128] = act( dc*( dc*Y[node] + sum_e dinv[r]*Y[r] ) + bias )
// One wave per node, slot-CSR. LPR lanes per row slice (16B/lane);
// G = 64/LPR edges per batch, 4-batch unroll. nblk = blocks per feature pass
// (pass = blockIdx.x / nblk selects the 128-col half).
template<int LPR, bool F16OUT, bool RELU>
__global__ __launch_bounds__(256) void k_agg(
    const int* __restrict__ deg, const float* __restrict__ dinv,
    const int* __restrict__ srcidx,
    const int2* __restrict__ ovf, const int* __restrict__ govf,
    const _Float16* __restrict__ Y, const float* __restrict__ bias,
    int N, int FT, int nblk,
    float* __restrict__ out32, _Float16* __restrict__ out16)
{
    const int G = 64 / LPR;   // edges per batch
    int pass = blockIdx.x / nblk;
    int bid  = blockIdx.x - pass * nblk;
    int node = bid * 4 + (threadIdx.x >> 6);
    if (node >= N) return;
    int lane = threadIdx.x & 63;
    int sub = lane / LPR;
    int fl  = lane % LPR;
    const int fcol = pass * 128 + fl * 8;

    float dc = dinv[node];
    int cnt = min(deg[node], CAP);
    const int beg = node * CAP;

    float acc[8];
    if (sub == 0) {  // self loop (scaled by dc; outer dc applied at the end)
        h8 v = *reinterpret_cast<const h8*>(&Y[(long)node * FT + fcol]);
        #pragma unroll
        for (int j = 0; j < 8; j++) acc[j] = dc * (float)v[j];
    } else {
        #pragma unroll
        for (int j = 0; j < 8; j++) acc[j] = 0.f;
    }

    int i = sub;
    int full = cnt / (4 * G);
    for (int t = 0; t < full; t++) {
        int r0 = srcidx[beg + i];
        int r1 = srcidx[beg + i + G];
        int r2 = srcidx[beg + i + 2 * G];
        int r3 = srcidx[beg + i + 3 * G];
        float d0 = dinv[r0], d1 = dinv[r1], d2 = dinv[r2], d3 = dinv[r3];
        h8 v0 = *reinterpret_cast<const h8*>(&Y[(long)r0 * FT + fcol]);
        h8 v1 = *reinterpret_cast<const h8*>(&Y[(long)r1 * FT + fcol]);
        h8 v2 = *reinterpret_cast<const h8*>(&Y[(long)r2 * FT + fcol]);
        h8 v3 = *reinterpret_cast<const h8*>(&Y[(long)r3 * FT + fcol]);
        #pragma unroll
        for (int j = 0; j < 8; j++)
            acc[j] += (d0 * (float)v0[j] + d1 * (float)v1[j]) +
                      (d2 * (float)v2[j] + d3 * (float)v3[j]);
        i += 4 * G;
    }
    for (; i < cnt; i += G) {
        int r = srcidx[beg + i];
        float d = dinv[r];
        h8 v = *reinterpret_cast<const h8*>(&Y[(long)r * FT + fcol]);
        #pragma unroll
        for (int j = 0; j < 8; j++) acc[j] += d * (float)v[j];
    }
    {   // capacity-overflow edges (normally zero)
        int no = *govf;
        for (int t = sub; t < no; t += G) {
            int2 pr = ovf[t];
            if (pr.y == node) {
                float d = dinv[pr.x];
                h8 v = *reinterpret_cast<const h8*>(&Y[(long)pr.x * FT + fcol]);
                #pragma unroll
                for (int j = 0; j < 8; j++) acc[j] += d * (float)v[j];
            }
        }
    }

    // merge sub-groups
    #pragma unroll
    for (int m = LPR; m < 64; m <<= 1)
        #pragma unroll
        for (int j = 0; j < 8; j++)
            acc[j] += __shfl_xor(acc[j], m, 64);

    const float4* b4 = reinterpret_cast<const float4*>(&bias[fcol]);
    float4 blo = b4[0], bhi = b4[1];
    float r8[8];
    r8[0] = fmaf(dc, acc[0], blo.x); r8[1] = fmaf(dc, acc[1], blo.y);
    r8[2] = fmaf(dc, acc[2], blo.z); r8[3] = fmaf(dc, acc[3], blo.w);
    r8[4] = fmaf(dc, acc[4], bhi.x); r8[5] = fmaf(dc, acc[5], bhi.y);
    r8[6] = fmaf(dc, acc[6], bhi.z); r8[7] = fmaf(dc, acc[7], bhi.w);
    if (RELU) {
        #pragma unroll
        for (int j = 0; j < 8; j++) r8[j] = fmaxf(r8[j], 0.f);
    }

    long base = (long)node * FT + fcol;
    if (F16OUT) {
        if (sub == 0) {
            h8 o;
            #pragma unroll
            for (int j = 0; j < 8; j++) o[j] = (_Float16)r8[j];
            *reinterpret_cast<h8*>(&out16[base]) = o;
        }
    } else {
        if (sub == 0) {
            *reinterpret_cast<float4*>(&out32[base]) =
                make_float4(r8[0], r8[1], r8[2], r8[3]);
        } else if (sub == 1) {
            *reinterpret_cast<float4*>(&out32[base + 4]) =
                make_float4(r8[4], r8[5], r8[6], r8[7]);
        }
    }
}

extern "C" void kernel_launch(void* const* d_in, const int* in_sizes, int n_in,
                              void* d_out, int out_size, void* d_ws, size_t ws_size,
                              hipStream_t stream)
{
    const float* x   = (const float*)d_in[0];
    const int*   ei  = (const int*)d_in[1];
    const float* W1  = (const float*)d_in[2];
    const float* b1  = (const float*)d_in[3];
    const float* W2  = (const float*)d_in[4];
    const float* b2  = (const float*)d_in[5];

    const int nhid  = in_sizes[3];            // 256
    const int nfeat = in_sizes[5];            // 128
    const int N     = in_sizes[0] / nhid;     // 50000
    const int E     = in_sizes[1] / 2;        // 800000

    const int* row = ei;        // source
    const int* col = ei + E;    // target

    size_t cur = 0;
    auto alloc = [&](size_t bytes) {
        void* p = (char*)d_ws + cur;
        cur += (bytes + 255) & ~(size_t)255;
        return p;
    };
    int*       deg_i  = (int*)alloc((size_t)N * 4);      // contiguous with govf:
    int*       govf   = (int*)alloc(256);                // one memset covers both
    float*     dinv   = (float*)alloc((size_t)N * 4);
    int*       rank   = (int*)alloc((size_t)E * 4);
    int*       srcidx = (int*)alloc((size_t)N * CAP * 4);
    int2*      ovf    = (int2*)alloc((size_t)E * 8);
    _Float16*  wt1    = (_Float16*)alloc((size_t)nhid * nhid * 2);
    _Float16*  wt2    = (_Float16*)alloc((size_t)nhid * nfeat * 2);
    _Float16*  y16    = (_Float16*)alloc((size_t)N * nhid * 2);   // xw (unscaled)
    _Float16*  h16    = (_Float16*)alloc((size_t)N * nhid * 2);   // relu output
    _Float16*  y2     = (_Float16*)alloc((size_t)N * nfeat * 2);  // hw (unscaled)
    float*     out    = (float*)d_out;
    (void)ws_size; (void)n_in; (void)out_size;

    const int T = 256;
    const int zb = (N + T - 1) / T;
    const int gx = nhid / 128;
    const int gy = (N + 127) / 128;

    // ---- zero deg + govf (contiguous) via DMA ----
    size_t degpad = (((size_t)N * 4) + 255) & ~(size_t)255;
    hipMemsetAsync(deg_i, 0, degpad + 256, stream);

    // ---- count (1024 blocks, fast standalone shape) + weight prep ----
    {
        const int ncb = 1024;
        int pb = (nhid * (nhid + nfeat) + T - 1) / T;
        k_count_prep<<<ncb + pb, T, 0, stream>>>(
            col, E, deg_i, rank, ncb, W1, W2, wt1, wt2, nhid, nhid, nfeat);
    }

    // ---- fused: GEMM1 (782 tiles, first) || dinv || slot fill (1024 blk) ----
    {
        int ngb = gx * gy;
        k_gemm_fill<<<ngb + zb + 1024, T, 0, stream>>>(
            x, wt1, y16, N, nhid, nhid, ngb, gx,
            row, col, rank, E, deg_i, dinv, N, srcidx, ovf, govf, zb);
    }

    // ---- layer 1 aggregation: both feature-half passes, one launch ----
    {
        int nblk = (N + 3) / 4;
        k_agg<16, true, true><<<2 * nblk, T, 0, stream>>>(
            deg_i, dinv, srcidx, ovf, govf, y16, b1, N, nhid, nblk, nullptr, h16);
    }

    // ---- layer 2 ----
    {
        dim3 grid(nfeat / 128, (N + 127) / 128);
        k_gemm16<<<grid, T, 0, stream>>>(h16, wt2, y2, N, nhid, nfeat);
    }
    {
        int nblk = (N + 3) / 4;
        k_agg<16, false, false><<<nblk, T, 0, stream>>>(
            deg_i, dinv, srcidx, ovf, govf, y2, b2, N, nfeat, nblk, out, nullptr);
    }
}

// Round 13
// 184.726 us; speedup vs baseline: 1.0575x; 1.0124x over previous
//
#include <hip/hip_runtime.h>
#include <math.h>

// ---------------------------------------------------------------------------
// 2-layer GCN:  out = gcn(relu(gcn(x, W1, b1)), W2, b2)
// gcn(x,W,b)[c] = dinv[c] * ( dinv[c]*xw[c] + sum_{edges r->c} dinv[r]*xw[r] ) + b
//   where xw = x @ W (UNSCALED in y buffers), dinv = rsqrt(1 + indeg)
// Slot-CSR (no scan): srcidx[c*CAP + rank[e]], rank = degree-count atomicAdd
// return. memset(deg) -> count(1024)+W-prep -> GEMM1||dinv||fill ->
// agg1 half0 -> agg1 half1 (sequential: L2 working-set split) -> GEMM2 -> agg2.
// ---------------------------------------------------------------------------

typedef _Float16 h8 __attribute__((ext_vector_type(8)));
typedef float    f32x4 __attribute__((ext_vector_type(4)));

#define CAP 64   // slots per node; overflow list handles adversarial degrees

// ---- shared GEMM body (register-prefetch pipelined, UNSCALED output) ----
template<bool A32>
__device__ __forceinline__ void gemm_body(
    const float* __restrict__ X32, const _Float16* __restrict__ X16,
    const _Float16* __restrict__ Wt, _Float16* __restrict__ Y,
    int M, int K, int NC, int bx, int by)
{
    __shared__ _Float16 As[128][40];  // row stride 80B (16B-aligned)
    __shared__ _Float16 Bs[128][40];

    const int bn = bx * 128;
    const int bm = by * 128;
    const int tid = threadIdx.x;
    const int w = tid >> 6, l = tid & 63;
    const int wm = (w >> 1) * 64, wn = (w & 1) * 64;
    const int lr = l & 15, lg = l >> 4;

    const int arow = tid >> 2, acol = (tid & 3) * 8;   // A32 loader
    const int xrow = tid >> 1, xcol = (tid & 1) * 16;  // fp16 A / B loader

    f32x4 acc[4][4];
    #pragma unroll
    for (int i = 0; i < 4; i++)
        #pragma unroll
        for (int j = 0; j < 4; j++)
            acc[i][j] = (f32x4){0.f, 0.f, 0.f, 0.f};

    float4 pf0, pf1, pf2, pf3;   // A32 prefetch regs
    h8 pa0, pa1;                 // fp16-A prefetch regs
    h8 pb0, pb1;                 // B prefetch regs

    auto loadA = [&](int k0) {
        if (A32) {
            int gm0 = bm + arow;      if (gm0 >= M) gm0 = M - 1;
            int gm1 = bm + 64 + arow; if (gm1 >= M) gm1 = M - 1;
            pf0 = *reinterpret_cast<const float4*>(&X32[(long)gm0 * K + k0 + acol]);
            pf1 = *reinterpret_cast<const float4*>(&X32[(long)gm0 * K + k0 + acol + 4]);
            pf2 = *reinterpret_cast<const float4*>(&X32[(long)gm1 * K + k0 + acol]);
            pf3 = *reinterpret_cast<const float4*>(&X32[(long)gm1 * K + k0 + acol + 4]);
        } else {
            int gm = bm + xrow; if (gm >= M) gm = M - 1;
            pa0 = *reinterpret_cast<const h8*>(&X16[(long)gm * K + k0 + xcol]);
            pa1 = *reinterpret_cast<const h8*>(&X16[(long)gm * K + k0 + xcol + 8]);
        }
    };
    auto loadB = [&](int k0) {
        pb0 = *reinterpret_cast<const h8*>(&Wt[(long)(bn + xrow) * K + k0 + xcol]);
        pb1 = *reinterpret_cast<const h8*>(&Wt[(long)(bn + xrow) * K + k0 + xcol + 8]);
    };

    loadA(0); loadB(0);
    for (int k0 = 0; k0 < K; k0 += 32) {
        if (A32) {
            h8 h0, h1;
            h0[0] = (_Float16)pf0.x; h0[1] = (_Float16)pf0.y;
            h0[2] = (_Float16)pf0.z; h0[3] = (_Float16)pf0.w;
            h0[4] = (_Float16)pf1.x; h0[5] = (_Float16)pf1.y;
            h0[6] = (_Float16)pf1.z; h0[7] = (_Float16)pf1.w;
            h1[0] = (_Float16)pf2.x; h1[1] = (_Float16)pf2.y;
            h1[2] = (_Float16)pf2.z; h1[3] = (_Float16)pf2.w;
            h1[4] = (_Float16)pf3.x; h1[5] = (_Float16)pf3.y;
            h1[6] = (_Float16)pf3.z; h1[7] = (_Float16)pf3.w;
            *reinterpret_cast<h8*>(&As[arow][acol]) = h0;
            *reinterpret_cast<h8*>(&As[64 + arow][acol]) = h1;
        } else {
            *reinterpret_cast<h8*>(&As[xrow][xcol]) = pa0;
            *reinterpret_cast<h8*>(&As[xrow][xcol + 8]) = pa1;
        }
        *reinterpret_cast<h8*>(&Bs[xrow][xcol]) = pb0;
        *reinterpret_cast<h8*>(&Bs[xrow][xcol + 8]) = pb1;
        __syncthreads();

        if (k0 + 32 < K) { loadA(k0 + 32); loadB(k0 + 32); }

        h8 a[4], b[4];
        #pragma unroll
        for (int i = 0; i < 4; i++)
            a[i] = *reinterpret_cast<const h8*>(&As[wm + i * 16 + lr][lg * 8]);
        #pragma unroll
        for (int j = 0; j < 4; j++)
            b[j] = *reinterpret_cast<const h8*>(&Bs[wn + j * 16 + lr][lg * 8]);
        #pragma unroll
        for (int i = 0; i < 4; i++)
            #pragma unroll
            for (int j = 0; j < 4; j++)
                acc[i][j] = __builtin_amdgcn_mfma_f32_16x16x32_f16(
                    a[i], b[j], acc[i][j], 0, 0, 0);
        __syncthreads();
    }

    // C layout: row = (l>>4)*4 + reg, col = l&15 ; unscaled store
    #pragma unroll
    for (int i = 0; i < 4; i++) {
        #pragma unroll
        for (int r = 0; r < 4; r++) {
            int gm = bm + wm + i * 16 + lg * 4 + r;
            if (gm < M) {
                #pragma unroll
                for (int j = 0; j < 4; j++)
                    Y[(long)gm * NC + bn + wn + j * 16 + lr] =
                        (_Float16)acc[i][j][r];
            }
        }
    }
}

// count (1024 blocks, the empirically-fast standalone shape) + weight prep
__global__ __launch_bounds__(256) void k_count_prep(
    const int* __restrict__ col, int E, int* __restrict__ deg, int* __restrict__ rank,
    int ncb,
    const float* __restrict__ W1, const float* __restrict__ W2,
    _Float16* __restrict__ wt1, _Float16* __restrict__ wt2,
    int K, int n1, int n2)
{
    if ((int)blockIdx.x < ncb) {
        int i = blockIdx.x * blockDim.x + threadIdx.x;
        int s = ncb * blockDim.x;
        for (int e = i; e < E; e += s) rank[e] = atomicAdd(&deg[col[e]], 1);
        return;
    }
    int i = (blockIdx.x - ncb) * blockDim.x + threadIdx.x;
    int c1 = K * n1;
    if (i < c1) {
        int k = i / n1, n = i % n1;
        wt1[(long)n * K + k] = (_Float16)W1[i];
    } else if (i < c1 + K * n2) {
        int j = i - c1;
        int k = j / n2, n = j % n2;
        wt2[(long)n * K + k] = (_Float16)W2[j];
    }
}

// Fused: blocks [0,ngb) = GEMM1 tiles (first, the long pole);
// [ngb, ngb+zb) = dinv; rest = atomic-free slot fill.
__global__ __launch_bounds__(256) void k_gemm_fill(
    const float* __restrict__ X32, const _Float16* __restrict__ Wt,
    _Float16* __restrict__ Y, int M, int K, int NC, int ngb, int gx,
    const int* __restrict__ row, const int* __restrict__ col,
    const int* __restrict__ rank, int E,
    const int* __restrict__ deg, float* __restrict__ dinv, int N,
    int* __restrict__ srcidx, int2* __restrict__ ovf, int* __restrict__ govf,
    int zb)
{
    if ((int)blockIdx.x < ngb) {
        int gb = blockIdx.x;
        gemm_body<true>(X32, nullptr, Wt, Y, M, K, NC, gb % gx, gb / gx);
        return;
    }
    if ((int)blockIdx.x < ngb + zb) {
        int i = (blockIdx.x - ngb) * blockDim.x + threadIdx.x;
        if (i < N) dinv[i] = rsqrtf(1.f + (float)deg[i]);
        return;
    }
    int g = (blockIdx.x - ngb - zb) * blockDim.x + threadIdx.x;
    int nthreads = (gridDim.x - ngb - zb) * blockDim.x;
    if ((E & 3) == 0) {
        int G4 = E >> 2;
        for (int q = g; q < G4; q += nthreads) {
            int e = q << 2;
            int4 c4 = *reinterpret_cast<const int4*>(&col[e]);
            int4 r4 = *reinterpret_cast<const int4*>(&row[e]);
            int4 k4 = *reinterpret_cast<const int4*>(&rank[e]);
            if (k4.x < CAP) srcidx[c4.x * CAP + k4.x] = r4.x;
            else { int o = atomicAdd(govf, 1); ovf[o] = make_int2(r4.x, c4.x); }
            if (k4.y < CAP) srcidx[c4.y * CAP + k4.y] = r4.y;
            else { int o = atomicAdd(govf, 1); ovf[o] = make_int2(r4.y, c4.y); }
            if (k4.z < CAP) srcidx[c4.z * CAP + k4.z] = r4.z;
            else { int o = atomicAdd(govf, 1); ovf[o] = make_int2(r4.z, c4.z); }
            if (k4.w < CAP) srcidx[c4.w * CAP + k4.w] = r4.w;
            else { int o = atomicAdd(govf, 1); ovf[o] = make_int2(r4.w, c4.w); }
        }
    } else {
        for (int e = g; e < E; e += nthreads) {
            int c = col[e], r = row[e], k = rank[e];
            if (k < CAP) srcidx[c * CAP + k] = r;
            else { int o = atomicAdd(govf, 1); ovf[o] = make_int2(r, c); }
        }
    }
}

__global__ __launch_bounds__(256) void k_gemm16(
    const _Float16* __restrict__ X16, const _Float16* __restrict__ Wt,
    _Float16* __restrict__ Y, int M, int K, int NC)
{
    gemm_body<false>(nullptr, X16, Wt, Y, M, K, NC, blockIdx.x, blockIdx.y);
}

// out[node][fo:fo+128] = act( dc*( dc*Y[node] + sum_e dinv[r]*Y[r] ) + bias )
// One wave per node, slot-CSR. 16 lanes per row slice (16B/lane), 4 sub-groups.
// Each sub-group loads 4 contiguous slot indices as one int4 -> 16 edges per
// wave iteration; fma with (float)fp16 source encourages v_fma_mix_f32.
template<bool F16OUT, bool RELU>
__global__ __launch_bounds__(256) void k_agg(
    const int* __restrict__ deg, const float* __restrict__ dinv,
    const int* __restrict__ srcidx,
    const int2* __restrict__ ovf, const int* __restrict__ govf,
    const _Float16* __restrict__ Y, const float* __restrict__ bias,
    int N, int FT, int fo,
    float* __restrict__ out32, _Float16* __restrict__ out16)
{
    int node = blockIdx.x * 4 + (threadIdx.x >> 6);
    if (node >= N) return;
    int lane = threadIdx.x & 63;
    int sub = lane >> 4;        // 0..3
    int fl  = lane & 15;        // 0..15
    const int fcol = fo + fl * 8;

    float dc = dinv[node];
    int cnt = min(deg[node], CAP);
    const int beg = node * CAP;

    float acc[8];
    if (sub == 0) {  // self loop (scaled by dc; outer dc applied at the end)
        h8 v = *reinterpret_cast<const h8*>(&Y[(long)node * FT + fcol]);
        #pragma unroll
        for (int j = 0; j < 8; j++) acc[j] = dc * (float)v[j];
    } else {
        #pragma unroll
        for (int j = 0; j < 8; j++) acc[j] = 0.f;
    }

    int base16 = cnt & ~15;     // full 16-edge groups
    for (int i = sub * 4; i < base16; i += 16) {
        int4 r4 = *reinterpret_cast<const int4*>(&srcidx[beg + i]);
        float d0 = dinv[r4.x], d1 = dinv[r4.y], d2 = dinv[r4.z], d3 = dinv[r4.w];
        h8 v0 = *reinterpret_cast<const h8*>(&Y[(long)r4.x * FT + fcol]);
        h8 v1 = *reinterpret_cast<const h8*>(&Y[(long)r4.y * FT + fcol]);
        h8 v2 = *reinterpret_cast<const h8*>(&Y[(long)r4.z * FT + fcol]);
        h8 v3 = *reinterpret_cast<const h8*>(&Y[(long)r4.w * FT + fcol]);
        #pragma unroll
        for (int j = 0; j < 8; j++) {
            acc[j] = fmaf(d0, (float)v0[j], acc[j]);
            acc[j] = fmaf(d1, (float)v1[j], acc[j]);
            acc[j] = fmaf(d2, (float)v2[j], acc[j]);
            acc[j] = fmaf(d3, (float)v3[j], acc[j]);
        }
    }
    for (int i = base16 + sub; i < cnt; i += 4) {
        int r = srcidx[beg + i];
        float d = dinv[r];
        h8 v = *reinterpret_cast<const h8*>(&Y[(long)r * FT + fcol]);
        #pragma unroll
        for (int j = 0; j < 8; j++) acc[j] = fmaf(d, (float)v[j], acc[j]);
    }
    {   // capacity-overflow edges (normally zero)
        int no = *govf;
        for (int t = sub; t < no; t += 4) {
            int2 pr = ovf[t];
            if (pr.y == node) {
                float d = dinv[pr.x];
                h8 v = *reinterpret_cast<const h8*>(&Y[(long)pr.x * FT + fcol]);
                #pragma unroll
                for (int j = 0; j < 8; j++) acc[j] = fmaf(d, (float)v[j], acc[j]);
            }
        }
    }

    // merge the 4 sub-groups
    #pragma unroll
    for (int m = 16; m < 64; m <<= 1)
        #pragma unroll
        for (int j = 0; j < 8; j++)
            acc[j] += __shfl_xor(acc[j], m, 64);

    const float4* b4 = reinterpret_cast<const float4*>(&bias[fcol]);
    float4 blo = b4[0], bhi = b4[1];
    float r8[8];
    r8[0] = fmaf(dc, acc[0], blo.x); r8[1] = fmaf(dc, acc[1], blo.y);
    r8[2] = fmaf(dc, acc[2], blo.z); r8[3] = fmaf(dc, acc[3], blo.w);
    r8[4] = fmaf(dc, acc[4], bhi.x); r8[5] = fmaf(dc, acc[5], bhi.y);
    r8[6] = fmaf(dc, acc[6], bhi.z); r8[7] = fmaf(dc, acc[7], bhi.w);
    if (RELU) {
        #pragma unroll
        for (int j = 0; j < 8; j++) r8[j] = fmaxf(r8[j], 0.f);
    }

    long base = (long)node * FT + fcol;
    if (F16OUT) {
        if (sub == 0) {
            h8 o;
            #pragma unroll
            for (int j = 0; j < 8; j++) o[j] = (_Float16)r8[j];
            *reinterpret_cast<h8*>(&out16[base]) = o;
        }
    } else {
        if (sub == 0) {
            *reinterpret_cast<float4*>(&out32[base]) =
                make_float4(r8[0], r8[1], r8[2], r8[3]);
        } else if (sub == 1) {
            *reinterpret_cast<float4*>(&out32[base + 4]) =
                make_float4(r8[4], r8[5], r8[6], r8[7]);
        }
    }
}

extern "C" void kernel_launch(void* const* d_in, const int* in_sizes, int n_in,
                              void* d_out, int out_size, void* d_ws, size_t ws_size,
                              hipStream_t stream)
{
    const float* x   = (const float*)d_in[0];
    const int*   ei  = (const int*)d_in[1];
    const float* W1  = (const float*)d_in[2];
    const float* b1  = (const float*)d_in[3];
    const float* W2  = (const float*)d_in[4];
    const float* b2  = (const float*)d_in[5];

    const int nhid  = in_sizes[3];            // 256
    const int nfeat = in_sizes[5];            // 128
    const int N     = in_sizes[0] / nhid;     // 50000
    const int E     = in_sizes[1] / 2;        // 800000

    const int* row = ei;        // source
    const int* col = ei + E;    // target

    size_t cur = 0;
    auto alloc = [&](size_t bytes) {
        void* p = (char*)d_ws + cur;
        cur += (bytes + 255) & ~(size_t)255;
        return p;
    };
    int*       deg_i  = (int*)alloc((size_t)N * 4);      // contiguous with govf:
    int*       govf   = (int*)alloc(256);                // one memset covers both
    float*     dinv   = (float*)alloc((size_t)N * 4);
    int*       rank   = (int*)alloc((size_t)E * 4);
    int*       srcidx = (int*)alloc((size_t)N * CAP * 4);
    int2*      ovf    = (int2*)alloc((size_t)E * 8);
    _Float16*  wt1    = (_Float16*)alloc((size_t)nhid * nhid * 2);
    _Float16*  wt2    = (_Float16*)alloc((size_t)nhid * nfeat * 2);
    _Float16*  y16    = (_Float16*)alloc((size_t)N * nhid * 2);   // xw (unscaled)
    _Float16*  h16    = (_Float16*)alloc((size_t)N * nhid * 2);   // relu output
    _Float16*  y2     = (_Float16*)alloc((size_t)N * nfeat * 2);  // hw (unscaled)
    float*     out    = (float*)d_out;
    (void)ws_size; (void)n_in; (void)out_size;

    const int T = 256;
    const int zb = (N + T - 1) / T;
    const int gx = nhid / 128;
    const int gy = (N + 127) / 128;

    // ---- zero deg + govf (contiguous) via DMA ----
    size_t degpad = (((size_t)N * 4) + 255) & ~(size_t)255;
    hipMemsetAsync(deg_i, 0, degpad + 256, stream);

    // ---- count (1024 blocks) + weight prep ----
    {
        const int ncb = 1024;
        int pb = (nhid * (nhid + nfeat) + T - 1) / T;
        k_count_prep<<<ncb + pb, T, 0, stream>>>(
            col, E, deg_i, rank, ncb, W1, W2, wt1, wt2, nhid, nhid, nfeat);
    }

    // ---- fused: GEMM1 (first) || dinv || slot fill (1024 blocks) ----
    {
        int ngb = gx * gy;
        k_gemm_fill<<<ngb + zb + 1024, T, 0, stream>>>(
            x, wt1, y16, N, nhid, nhid, ngb, gx,
            row, col, rank, E, deg_i, dinv, N, srcidx, ovf, govf, zb);
    }

    // ---- layer 1 aggregation: two SEQUENTIAL feature-half passes ----
    {
        int nblk = (N + 3) / 4;
        k_agg<true, true><<<nblk, T, 0, stream>>>(
            deg_i, dinv, srcidx, ovf, govf, y16, b1, N, nhid, 0, nullptr, h16);
        k_agg<true, true><<<nblk, T, 0, stream>>>(
            deg_i, dinv, srcidx, ovf, govf, y16, b1, N, nhid, 128, nullptr, h16);
    }

    // ---- layer 2 ----
    {
        dim3 grid(nfeat / 128, (N + 127) / 128);
        k_gemm16<<<grid, T, 0, stream>>>(h16, wt2, y2, N, nhid, nfeat);
    }
    {
        int nblk = (N + 3) / 4;
        k_agg<false, false><<<nblk, T, 0, stream>>>(
            deg_i, dinv, srcidx, ovf, govf, y2, b2, N, nfeat, 0, out, nullptr);
    }
}

// Round 14
// 184.669 us; speedup vs baseline: 1.0578x; 1.0003x over previous
//
#include <hip/hip_runtime.h>
#include <math.h>

// ---------------------------------------------------------------------------
// 2-layer GCN:  out = gcn(relu(gcn(x, W1, b1)), W2, b2)
// gcn(x,W,b)[c] = dinv[c] * ( dinv[c]*xw[c] + sum_{edges r->c} dinv[r]*xw[r] ) + b
//   where xw = x @ W (UNSCALED in y buffers), dinv = rsqrt(1 + indeg)
// Slot-CSR (no scan): srcidx[c*CAP + rank[e]], rank = degree-count atomicAdd
// return. k_zero(deg) -> count(1024)+W-prep -> GEMM1||dinv||fill ->
// agg1 half0 -> agg1 half1 (sequential: L2 working-set split) -> GEMM2 -> agg2.
// (hipMemsetAsync replaced by k_zero: the rocclr fill kernel cost ~39us for
//  a 200KB zero in the graph -- measured R13.)
// ---------------------------------------------------------------------------

typedef _Float16 h8 __attribute__((ext_vector_type(8)));
typedef float    f32x4 __attribute__((ext_vector_type(4)));

#define CAP 64   // slots per node; overflow list handles adversarial degrees

__global__ void k_zero(int* __restrict__ deg, int* __restrict__ govf, int N) {
    int i = blockIdx.x * blockDim.x + threadIdx.x;
    if (i < N) deg[i] = 0;
    if (i == 0) *govf = 0;
}

// ---- shared GEMM body (register-prefetch pipelined, UNSCALED output) ----
template<bool A32>
__device__ __forceinline__ void gemm_body(
    const float* __restrict__ X32, const _Float16* __restrict__ X16,
    const _Float16* __restrict__ Wt, _Float16* __restrict__ Y,
    int M, int K, int NC, int bx, int by)
{
    __shared__ _Float16 As[128][40];  // row stride 80B (16B-aligned)
    __shared__ _Float16 Bs[128][40];

    const int bn = bx * 128;
    const int bm = by * 128;
    const int tid = threadIdx.x;
    const int w = tid >> 6, l = tid & 63;
    const int wm = (w >> 1) * 64, wn = (w & 1) * 64;
    const int lr = l & 15, lg = l >> 4;

    const int arow = tid >> 2, acol = (tid & 3) * 8;   // A32 loader
    const int xrow = tid >> 1, xcol = (tid & 1) * 16;  // fp16 A / B loader

    f32x4 acc[4][4];
    #pragma unroll
    for (int i = 0; i < 4; i++)
        #pragma unroll
        for (int j = 0; j < 4; j++)
            acc[i][j] = (f32x4){0.f, 0.f, 0.f, 0.f};

    float4 pf0, pf1, pf2, pf3;   // A32 prefetch regs
    h8 pa0, pa1;                 // fp16-A prefetch regs
    h8 pb0, pb1;                 // B prefetch regs

    auto loadA = [&](int k0) {
        if (A32) {
            int gm0 = bm + arow;      if (gm0 >= M) gm0 = M - 1;
            int gm1 = bm + 64 + arow; if (gm1 >= M) gm1 = M - 1;
            pf0 = *reinterpret_cast<const float4*>(&X32[(long)gm0 * K + k0 + acol]);
            pf1 = *reinterpret_cast<const float4*>(&X32[(long)gm0 * K + k0 + acol + 4]);
            pf2 = *reinterpret_cast<const float4*>(&X32[(long)gm1 * K + k0 + acol]);
            pf3 = *reinterpret_cast<const float4*>(&X32[(long)gm1 * K + k0 + acol + 4]);
        } else {
            int gm = bm + xrow; if (gm >= M) gm = M - 1;
            pa0 = *reinterpret_cast<const h8*>(&X16[(long)gm * K + k0 + xcol]);
            pa1 = *reinterpret_cast<const h8*>(&X16[(long)gm * K + k0 + xcol + 8]);
        }
    };
    auto loadB = [&](int k0) {
        pb0 = *reinterpret_cast<const h8*>(&Wt[(long)(bn + xrow) * K + k0 + xcol]);
        pb1 = *reinterpret_cast<const h8*>(&Wt[(long)(bn + xrow) * K + k0 + xcol + 8]);
    };

    loadA(0); loadB(0);
    for (int k0 = 0; k0 < K; k0 += 32) {
        if (A32) {
            h8 h0, h1;
            h0[0] = (_Float16)pf0.x; h0[1] = (_Float16)pf0.y;
            h0[2] = (_Float16)pf0.z; h0[3] = (_Float16)pf0.w;
            h0[4] = (_Float16)pf1.x; h0[5] = (_Float16)pf1.y;
            h0[6] = (_Float16)pf1.z; h0[7] = (_Float16)pf1.w;
            h1[0] = (_Float16)pf2.x; h1[1] = (_Float16)pf2.y;
            h1[2] = (_Float16)pf2.z; h1[3] = (_Float16)pf2.w;
            h1[4] = (_Float16)pf3.x; h1[5] = (_Float16)pf3.y;
            h1[6] = (_Float16)pf3.z; h1[7] = (_Float16)pf3.w;
            *reinterpret_cast<h8*>(&As[arow][acol]) = h0;
            *reinterpret_cast<h8*>(&As[64 + arow][acol]) = h1;
        } else {
            *reinterpret_cast<h8*>(&As[xrow][xcol]) = pa0;
            *reinterpret_cast<h8*>(&As[xrow][xcol + 8]) = pa1;
        }
        *reinterpret_cast<h8*>(&Bs[xrow][xcol]) = pb0;
        *reinterpret_cast<h8*>(&Bs[xrow][xcol + 8]) = pb1;
        __syncthreads();

        if (k0 + 32 < K) { loadA(k0 + 32); loadB(k0 + 32); }

        h8 a[4], b[4];
        #pragma unroll
        for (int i = 0; i < 4; i++)
            a[i] = *reinterpret_cast<const h8*>(&As[wm + i * 16 + lr][lg * 8]);
        #pragma unroll
        for (int j = 0; j < 4; j++)
            b[j] = *reinterpret_cast<const h8*>(&Bs[wn + j * 16 + lr][lg * 8]);
        #pragma unroll
        for (int i = 0; i < 4; i++)
            #pragma unroll
            for (int j = 0; j < 4; j++)
                acc[i][j] = __builtin_amdgcn_mfma_f32_16x16x32_f16(
                    a[i], b[j], acc[i][j], 0, 0, 0);
        __syncthreads();
    }

    // C layout: row = (l>>4)*4 + reg, col = l&15 ; unscaled store
    #pragma unroll
    for (int i = 0; i < 4; i++) {
        #pragma unroll
        for (int r = 0; r < 4; r++) {
            int gm = bm + wm + i * 16 + lg * 4 + r;
            if (gm < M) {
                #pragma unroll
                for (int j = 0; j < 4; j++)
                    Y[(long)gm * NC + bn + wn + j * 16 + lr] =
                        (_Float16)acc[i][j][r];
            }
        }
    }
}

// count (1024 blocks, the empirically-fast standalone shape) + weight prep
__global__ __launch_bounds__(256) void k_count_prep(
    const int* __restrict__ col, int E, int* __restrict__ deg, int* __restrict__ rank,
    int ncb,
    const float* __restrict__ W1, const float* __restrict__ W2,
    _Float16* __restrict__ wt1, _Float16* __restrict__ wt2,
    int K, int n1, int n2)
{
    if ((int)blockIdx.x < ncb) {
        int i = blockIdx.x * blockDim.x + threadIdx.x;
        int s = ncb * blockDim.x;
        for (int e = i; e < E; e += s) rank[e] = atomicAdd(&deg[col[e]], 1);
        return;
    }
    int i = (blockIdx.x - ncb) * blockDim.x + threadIdx.x;
    int c1 = K * n1;
    if (i < c1) {
        int k = i / n1, n = i % n1;
        wt1[(long)n * K + k] = (_Float16)W1[i];
    } else if (i < c1 + K * n2) {
        int j = i - c1;
        int k = j / n2, n = j % n2;
        wt2[(long)n * K + k] = (_Float16)W2[j];
    }
}

// Fused: blocks [0,ngb) = GEMM1 tiles (first, the long pole);
// [ngb, ngb+zb) = dinv; rest = atomic-free slot fill.
__global__ __launch_bounds__(256) void k_gemm_fill(
    const float* __restrict__ X32, const _Float16* __restrict__ Wt,
    _Float16* __restrict__ Y, int M, int K, int NC, int ngb, int gx,
    const int* __restrict__ row, const int* __restrict__ col,
    const int* __restrict__ rank, int E,
    const int* __restrict__ deg, float* __restrict__ dinv, int N,
    int* __restrict__ srcidx, int2* __restrict__ ovf, int* __restrict__ govf,
    int zb)
{
    if ((int)blockIdx.x < ngb) {
        int gb = blockIdx.x;
        gemm_body<true>(X32, nullptr, Wt, Y, M, K, NC, gb % gx, gb / gx);
        return;
    }
    if ((int)blockIdx.x < ngb + zb) {
        int i = (blockIdx.x - ngb) * blockDim.x + threadIdx.x;
        if (i < N) dinv[i] = rsqrtf(1.f + (float)deg[i]);
        return;
    }
    int g = (blockIdx.x - ngb - zb) * blockDim.x + threadIdx.x;
    int nthreads = (gridDim.x - ngb - zb) * blockDim.x;
    if ((E & 3) == 0) {
        int G4 = E >> 2;
        for (int q = g; q < G4; q += nthreads) {
            int e = q << 2;
            int4 c4 = *reinterpret_cast<const int4*>(&col[e]);
            int4 r4 = *reinterpret_cast<const int4*>(&row[e]);
            int4 k4 = *reinterpret_cast<const int4*>(&rank[e]);
            if (k4.x < CAP) srcidx[c4.x * CAP + k4.x] = r4.x;
            else { int o = atomicAdd(govf, 1); ovf[o] = make_int2(r4.x, c4.x); }
            if (k4.y < CAP) srcidx[c4.y * CAP + k4.y] = r4.y;
            else { int o = atomicAdd(govf, 1); ovf[o] = make_int2(r4.y, c4.y); }
            if (k4.z < CAP) srcidx[c4.z * CAP + k4.z] = r4.z;
            else { int o = atomicAdd(govf, 1); ovf[o] = make_int2(r4.z, c4.z); }
            if (k4.w < CAP) srcidx[c4.w * CAP + k4.w] = r4.w;
            else { int o = atomicAdd(govf, 1); ovf[o] = make_int2(r4.w, c4.w); }
        }
    } else {
        for (int e = g; e < E; e += nthreads) {
            int c = col[e], r = row[e], k = rank[e];
            if (k < CAP) srcidx[c * CAP + k] = r;
            else { int o = atomicAdd(govf, 1); ovf[o] = make_int2(r, c); }
        }
    }
}

__global__ __launch_bounds__(256) void k_gemm16(
    const _Float16* __restrict__ X16, const _Float16* __restrict__ Wt,
    _Float16* __restrict__ Y, int M, int K, int NC)
{
    gemm_body<false>(nullptr, X16, Wt, Y, M, K, NC, blockIdx.x, blockIdx.y);
}

// out[node][fo:fo+128] = act( dc*( dc*Y[node] + sum_e dinv[r]*Y[r] ) + bias )
// One wave per node, slot-CSR. 16 lanes per row slice (16B/lane), 4 sub-groups.
// Each sub-group loads 4 contiguous slot indices as one int4 -> 16 edges per
// wave iteration; fma with (float)fp16 source encourages v_fma_mix_f32.
template<bool F16OUT, bool RELU>
__global__ __launch_bounds__(256) void k_agg(
    const int* __restrict__ deg, const float* __restrict__ dinv,
    const int* __restrict__ srcidx,
    const int2* __restrict__ ovf, const int* __restrict__ govf,
    const _Float16* __restrict__ Y, const float* __restrict__ bias,
    int N, int FT, int fo,
    float* __restrict__ out32, _Float16* __restrict__ out16)
{
    int node = blockIdx.x * 4 + (threadIdx.x >> 6);
    if (node >= N) return;
    int lane = threadIdx.x & 63;
    int sub = lane >> 4;        // 0..3
    int fl  = lane & 15;        // 0..15
    const int fcol = fo + fl * 8;

    float dc = dinv[node];
    int cnt = min(deg[node], CAP);
    const int beg = node * CAP;

    float acc[8];
    if (sub == 0) {  // self loop (scaled by dc; outer dc applied at the end)
        h8 v = *reinterpret_cast<const h8*>(&Y[(long)node * FT + fcol]);
        #pragma unroll
        for (int j = 0; j < 8; j++) acc[j] = dc * (float)v[j];
    } else {
        #pragma unroll
        for (int j = 0; j < 8; j++) acc[j] = 0.f;
    }

    int base16 = cnt & ~15;     // full 16-edge groups
    for (int i = sub * 4; i < base16; i += 16) {
        int4 r4 = *reinterpret_cast<const int4*>(&srcidx[beg + i]);
        float d0 = dinv[r4.x], d1 = dinv[r4.y], d2 = dinv[r4.z], d3 = dinv[r4.w];
        h8 v0 = *reinterpret_cast<const h8*>(&Y[(long)r4.x * FT + fcol]);
        h8 v1 = *reinterpret_cast<const h8*>(&Y[(long)r4.y * FT + fcol]);
        h8 v2 = *reinterpret_cast<const h8*>(&Y[(long)r4.z * FT + fcol]);
        h8 v3 = *reinterpret_cast<const h8*>(&Y[(long)r4.w * FT + fcol]);
        #pragma unroll
        for (int j = 0; j < 8; j++) {
            acc[j] = fmaf(d0, (float)v0[j], acc[j]);
            acc[j] = fmaf(d1, (float)v1[j], acc[j]);
            acc[j] = fmaf(d2, (float)v2[j], acc[j]);
            acc[j] = fmaf(d3, (float)v3[j], acc[j]);
        }
    }
    for (int i = base16 + sub; i < cnt; i += 4) {
        int r = srcidx[beg + i];
        float d = dinv[r];
        h8 v = *reinterpret_cast<const h8*>(&Y[(long)r * FT + fcol]);
        #pragma unroll
        for (int j = 0; j < 8; j++) acc[j] = fmaf(d, (float)v[j], acc[j]);
    }
    {   // capacity-overflow edges (normally zero)
        int no = *govf;
        for (int t = sub; t < no; t += 4) {
            int2 pr = ovf[t];
            if (pr.y == node) {
                float d = dinv[pr.x];
                h8 v = *reinterpret_cast<const h8*>(&Y[(long)pr.x * FT + fcol]);
                #pragma unroll
                for (int j = 0; j < 8; j++) acc[j] = fmaf(d, (float)v[j], acc[j]);
            }
        }
    }

    // merge the 4 sub-groups
    #pragma unroll
    for (int m = 16; m < 64; m <<= 1)
        #pragma unroll
        for (int j = 0; j < 8; j++)
            acc[j] += __shfl_xor(acc[j], m, 64);

    const float4* b4 = reinterpret_cast<const float4*>(&bias[fcol]);
    float4 blo = b4[0], bhi = b4[1];
    float r8[8];
    r8[0] = fmaf(dc, acc[0], blo.x); r8[1] = fmaf(dc, acc[1], blo.y);
    r8[2] = fmaf(dc, acc[2], blo.z); r8[3] = fmaf(dc, acc[3], blo.w);
    r8[4] = fmaf(dc, acc[4], bhi.x); r8[5] = fmaf(dc, acc[5], bhi.y);
    r8[6] = fmaf(dc, acc[6], bhi.z); r8[7] = fmaf(dc, acc[7], bhi.w);
    if (RELU) {
        #pragma unroll
        for (int j = 0; j < 8; j++) r8[j] = fmaxf(r8[j], 0.f);
    }

    long base = (long)node * FT + fcol;
    if (F16OUT) {
        if (sub == 0) {
            h8 o;
            #pragma unroll
            for (int j = 0; j < 8; j++) o[j] = (_Float16)r8[j];
            *reinterpret_cast<h8*>(&out16[base]) = o;
        }
    } else {
        if (sub == 0) {
            *reinterpret_cast<float4*>(&out32[base]) =
                make_float4(r8[0], r8[1], r8[2], r8[3]);
        } else if (sub == 1) {
            *reinterpret_cast<float4*>(&out32[base + 4]) =
                make_float4(r8[4], r8[5], r8[6], r8[7]);
        }
    }
}

extern "C" void kernel_launch(void* const* d_in, const int* in_sizes, int n_in,
                              void* d_out, int out_size, void* d_ws, size_t ws_size,
                              hipStream_t stream)
{
    const float* x   = (const float*)d_in[0];
    const int*   ei  = (const int*)d_in[1];
    const float* W1  = (const float*)d_in[2];
    const float* b1  = (const float*)d_in[3];
    const float* W2  = (const float*)d_in[4];
    const float* b2  = (const float*)d_in[5];

    const int nhid  = in_sizes[3];            // 256
    const int nfeat = in_sizes[5];            // 128
    const int N     = in_sizes[0] / nhid;     // 50000
    const int E     = in_sizes[1] / 2;        // 800000

    const int* row = ei;        // source
    const int* col = ei + E;    // target

    size_t cur = 0;
    auto alloc = [&](size_t bytes) {
        void* p = (char*)d_ws + cur;
        cur += (bytes + 255) & ~(size_t)255;
        return p;
    };
    int*       deg_i  = (int*)alloc((size_t)N * 4);
    int*       govf   = (int*)alloc(256);
    float*     dinv   = (float*)alloc((size_t)N * 4);
    int*       rank   = (int*)alloc((size_t)E * 4);
    int*       srcidx = (int*)alloc((size_t)N * CAP * 4);
    int2*      ovf    = (int2*)alloc((size_t)E * 8);
    _Float16*  wt1    = (_Float16*)alloc((size_t)nhid * nhid * 2);
    _Float16*  wt2    = (_Float16*)alloc((size_t)nhid * nfeat * 2);
    _Float16*  y16    = (_Float16*)alloc((size_t)N * nhid * 2);   // xw (unscaled)
    _Float16*  h16    = (_Float16*)alloc((size_t)N * nhid * 2);   // relu output
    _Float16*  y2     = (_Float16*)alloc((size_t)N * nfeat * 2);  // hw (unscaled)
    float*     out    = (float*)d_out;
    (void)ws_size; (void)n_in; (void)out_size;

    const int T = 256;
    const int zb = (N + T - 1) / T;
    const int gx = nhid / 128;
    const int gy = (N + 127) / 128;

    // ---- zero deg + govf with a plain kernel (memset DMA path cost ~39us) ----
    k_zero<<<zb, T, 0, stream>>>(deg_i, govf, N);

    // ---- count (1024 blocks) + weight prep ----
    {
        const int ncb = 1024;
        int pb = (nhid * (nhid + nfeat) + T - 1) / T;
        k_count_prep<<<ncb + pb, T, 0, stream>>>(
            col, E, deg_i, rank, ncb, W1, W2, wt1, wt2, nhid, nhid, nfeat);
    }

    // ---- fused: GEMM1 (first) || dinv || slot fill (1024 blocks) ----
    {
        int ngb = gx * gy;
        k_gemm_fill<<<ngb + zb + 1024, T, 0, stream>>>(
            x, wt1, y16, N, nhid, nhid, ngb, gx,
            row, col, rank, E, deg_i, dinv, N, srcidx, ovf, govf, zb);
    }

    // ---- layer 1 aggregation: two SEQUENTIAL feature-half passes ----
    {
        int nblk = (N + 3) / 4;
        k_agg<true, true><<<nblk, T, 0, stream>>>(
            deg_i, dinv, srcidx, ovf, govf, y16, b1, N, nhid, 0, nullptr, h16);
        k_agg<true, true><<<nblk, T, 0, stream>>>(
            deg_i, dinv, srcidx, ovf, govf, y16, b1, N, nhid, 128, nullptr, h16);
    }

    // ---- layer 2 ----
    {
        dim3 grid(nfeat / 128, (N + 127) / 128);
        k_gemm16<<<grid, T, 0, stream>>>(h16, wt2, y2, N, nhid, nfeat);
    }
    {
        int nblk = (N + 3) / 4;
        k_agg<false, false><<<nblk, T, 0, stream>>>(
            deg_i, dinv, srcidx, ovf, govf, y2, b2, N, nfeat, 0, out, nullptr);
    }
}